// Round 4
// baseline (1111.765 us; speedup 1.0000x reference)
//
#include <hip/hip_runtime.h>

#define N_NODES 50000
#define N_EDGES 800000
#define N_GRAPHS 2048
#define IN_DIM 128
#define HID 256
#define N_LAYERS 4
#define BN_EPS 1e-5f

typedef unsigned short ushort_t;
typedef __bf16 bf16x8 __attribute__((ext_vector_type(8)));
typedef float f32x4 __attribute__((ext_vector_type(4)));

// ---- fp32 -> bf16 (round-to-nearest-even) helpers ----
__device__ __forceinline__ ushort_t f2bf_rn(float x) {
    unsigned int u = __float_as_uint(x);
    u += 0x7FFFu + ((u >> 16) & 1u);
    return (ushort_t)(u >> 16);
}
__device__ __forceinline__ float bf2f(ushort_t h) {
    return __uint_as_float(((unsigned int)h) << 16);
}

// ---- async global->LDS, 16B per lane ----
__device__ __forceinline__ void gl_lds16(const ushort_t* g, ushort_t* l) {
    __builtin_amdgcn_global_load_lds(
        (const __attribute__((address_space(1))) void*)g,
        (__attribute__((address_space(3))) void*)l, 16, 0, 0);
}

// ---------------- degree count ----------------
__global__ void k_deg(const int* __restrict__ dst, int* __restrict__ degi, int E) {
    int e = blockIdx.x * blockDim.x + threadIdx.x;
    if (e < E) atomicAdd(&degi[dst[e]], 1);
}

__global__ void k_nodenorm(const int* __restrict__ degi, float* __restrict__ dinv, int N) {
    int n = blockIdx.x * blockDim.x + threadIdx.x;
    if (n < N) {
        float d = 1.0f + (float)degi[n];
        dinv[n] = 1.0f / sqrtf(d);
    }
}

// ---------------- exclusive prefix scan (single block) ----------------
__global__ __launch_bounds__(1024) void k_scan(const int* __restrict__ degi,
                                               int* __restrict__ rowstart,
                                               int* __restrict__ cursor, int N) {
    __shared__ int part[1024];
    int t = threadIdx.x;
    int chunk = (N + 1023) / 1024;
    int b = t * chunk;
    int e = min(b + chunk, N);
    int s = 0;
    for (int i = b; i < e; ++i) s += degi[i];
    part[t] = s;
    __syncthreads();
    for (int off = 1; off < 1024; off <<= 1) {
        int v = (t >= off) ? part[t - off] : 0;
        __syncthreads();
        part[t] += v;
        __syncthreads();
    }
    int run = (t == 0) ? 0 : part[t - 1];
    for (int i = b; i < e; ++i) {
        rowstart[i] = run;
        cursor[i] = run;
        run += degi[i];
    }
    if (t == 1023) rowstart[N] = run;
}

// ---------------- CSR fill (src ids only; weights recomputed on the fly) ----------------
__global__ void k_fill(const int* __restrict__ src, const int* __restrict__ dst,
                       int* __restrict__ cursor, int* __restrict__ esrc, int E) {
    int e = blockIdx.x * blockDim.x + threadIdx.x;
    if (e >= E) return;
    int s = src[e], d = dst[e];
    int pos = atomicAdd(&cursor[d], 1);
    esrc[pos] = s;
}

// ---------------- split x -> bf16 hi/lo ----------------
__global__ __launch_bounds__(256) void k_splitx(const float* __restrict__ x,
                                                ushort_t* __restrict__ Ah,
                                                ushort_t* __restrict__ Al, int total4) {
    int i = blockIdx.x * blockDim.x + threadIdx.x;
    if (i >= total4) return;
    float4 v = ((const float4*)x)[i];
    ushort4 h, l;
    h.x = f2bf_rn(v.x); l.x = f2bf_rn(v.x - bf2f(h.x));
    h.y = f2bf_rn(v.y); l.y = f2bf_rn(v.y - bf2f(h.y));
    h.z = f2bf_rn(v.z); l.z = f2bf_rn(v.z - bf2f(h.z));
    h.w = f2bf_rn(v.w); l.w = f2bf_rn(v.w - bf2f(h.w));
    ((ushort4*)Ah)[i] = h;
    ((ushort4*)Al)[i] = l;
}

// ---------------- split + transpose weights -> [layer][n][k] bf16 hi/lo ----------------
__global__ void k_splitw(const float* __restrict__ W0, const float* __restrict__ Ws,
                         ushort_t* __restrict__ Wh, ushort_t* __restrict__ Wl) {
    int i = blockIdx.x * blockDim.x + threadIdx.x;
    const int total = 128 * 256 + 3 * 256 * 256;
    if (i >= total) return;
    float v;
    if (i < 32768) {
        int n = i >> 7, k = i & 127;
        v = W0[k * 256 + n];
    } else {
        int t = i - 32768;
        int l = t >> 16;
        int r = t & 65535;
        int n = r >> 8, k = r & 255;
        v = Ws[l * 65536 + k * 256 + n];
    }
    ushort_t h = f2bf_rn(v);
    Wh[i] = h;
    Wl[i] = f2bf_rn(v - bf2f(h));
}

// ---------------- MFMA split-bf16 GEMM: H = A[N x K] @ W[K x 256] ----------------
// 128x128 tile; 3-term split (AhWh + AhWl + AlWh); output H in CHUNK-MAJOR
// layout: H[chunk][node][16], chunk = col/16.
__global__ __launch_bounds__(256) void k_gemm(const ushort_t* __restrict__ Ah,
                                              const ushort_t* __restrict__ Al,
                                              const ushort_t* __restrict__ Wh,
                                              const ushort_t* __restrict__ Wl,
                                              float* __restrict__ H, int K) {
    __shared__ ushort_t sm[4 * 128 * 32]; // 32 KB: Ah|Al|Wh|Wl tiles
    ushort_t* tAh = sm;
    ushort_t* tAl = sm + 4096;
    ushort_t* tWh = sm + 8192;
    ushort_t* tWl = sm + 12288;

    int tid = threadIdx.x;
    int lane = tid & 63;
    int w = tid >> 6;
    int wrow = w & 1, wcol = w >> 1;
    int row0 = blockIdx.x * 128;
    int col0 = blockIdx.y * 128;

    const ushort_t* gsrc = (w == 0) ? Ah : (w == 1) ? Al : (w == 2) ? Wh : Wl;
    int rbase = (w < 2) ? row0 : col0;
    int rlimit = (w < 2) ? N_NODES : (col0 + 128);
    ushort_t* ldst = sm + w * 4096;
    int srow = lane >> 2;
    int sch = lane & 3;

    f32x4 acc[4][4] = {};
    int m = lane & 15, q = lane >> 4;

    for (int k0 = 0; k0 < K; k0 += 32) {
        #pragma unroll
        for (int i = 0; i < 8; ++i) {
            int r = i * 16 + srow;
            int grow = rbase + r;
            int gch = sch ^ (r & 3);
            if (grow < rlimit)
                gl_lds16(gsrc + (size_t)grow * K + k0 + gch * 8, ldst + i * 512);
        }
        __syncthreads();

        bf16x8 ahf[4], alf[4], whf[4], wlf[4];
        #pragma unroll
        for (int r = 0; r < 4; ++r) {
            int rr = wrow * 64 + r * 16 + m;
            int off = rr * 32 + ((q ^ (rr & 3)) << 3);
            ahf[r] = *(const bf16x8*)(tAh + off);
            alf[r] = *(const bf16x8*)(tAl + off);
        }
        #pragma unroll
        for (int c = 0; c < 4; ++c) {
            int nn = wcol * 64 + c * 16 + m;
            int off = nn * 32 + ((q ^ (nn & 3)) << 3);
            whf[c] = *(const bf16x8*)(tWh + off);
            wlf[c] = *(const bf16x8*)(tWl + off);
        }
        #pragma unroll
        for (int r = 0; r < 4; ++r)
            #pragma unroll
            for (int c = 0; c < 4; ++c) {
                acc[r][c] = __builtin_amdgcn_mfma_f32_16x16x32_bf16(ahf[r], whf[c], acc[r][c], 0, 0, 0);
                acc[r][c] = __builtin_amdgcn_mfma_f32_16x16x32_bf16(ahf[r], wlf[c], acc[r][c], 0, 0, 0);
                acc[r][c] = __builtin_amdgcn_mfma_f32_16x16x32_bf16(alf[r], whf[c], acc[r][c], 0, 0, 0);
            }
        __syncthreads();
    }

    #pragma unroll
    for (int r = 0; r < 4; ++r) {
        int mrow = row0 + wrow * 64 + r * 16 + (lane >> 4) * 4;
        #pragma unroll
        for (int c = 0; c < 4; ++c) {
            int n = col0 + wcol * 64 + c * 16 + (lane & 15);
            float* base = H + (size_t)(n >> 4) * (N_NODES * 16) + (n & 15);
            f32x4 v = acc[r][c];
            #pragma unroll
            for (int g = 0; g < 4; ++g)
                if (mrow + g < N_NODES)
                    base[(size_t)(mrow + g) * 16] = v[g];
        }
    }
}

// ---------------- BN prep (bias folded) ----------------
__global__ void k_bnprep(const float* __restrict__ gamma, const float* __restrict__ beta,
                         const float* __restrict__ mean, const float* __restrict__ var,
                         const float* __restrict__ bias,
                         float* __restrict__ scale, float* __restrict__ shift) {
    int l = blockIdx.x;
    int c = threadIdx.x;
    if (c < HID) {
        float s = gamma[l * HID + c] * rsqrtf(var[l * HID + c] + BN_EPS);
        scale[l * HID + c] = s;
        shift[l * HID + c] = beta[l * HID + c] + (bias[l * HID + c] - mean[l * HID + c]) * s;
    }
}

// ---------------- chunked gather: XCD-affine channel slices ----------------
// H chunk-major [16][N][16]. Grid = 10000 blocks; chunk = (blockIdx%8) + 8*phase.
// Block = 256 thr = 16 nodes x 16 ch; processes 80 consecutive nodes (5 batches).
// agg = dinv[n] * ( H[n]*dinv[n] + sum_s H[s]*dinv[s] ); then BN+ReLU.
#define NB_G 625
#define NPB_G 80

__device__ __forceinline__ float gather_val(const float* __restrict__ Hc,
                                            const int* __restrict__ rowstart,
                                            const int* __restrict__ esrc,
                                            const float* __restrict__ dinv,
                                            float sc, float sh, int node, int ch16) {
    int beg = rowstart[node];
    int end = rowstart[node + 1];
    float dn = dinv[node];
    float acc = Hc[(size_t)node * 16 + ch16] * dn;
    int j = beg;
    for (; j + 3 < end; j += 4) {
        int s0 = esrc[j], s1 = esrc[j + 1], s2 = esrc[j + 2], s3 = esrc[j + 3];
        float w0 = dinv[s0], w1 = dinv[s1], w2 = dinv[s2], w3 = dinv[s3];
        float v0 = Hc[(size_t)s0 * 16 + ch16];
        float v1 = Hc[(size_t)s1 * 16 + ch16];
        float v2 = Hc[(size_t)s2 * 16 + ch16];
        float v3 = Hc[(size_t)s3 * 16 + ch16];
        acc = fmaf(v0, w0, acc);
        acc = fmaf(v1, w1, acc);
        acc = fmaf(v2, w2, acc);
        acc = fmaf(v3, w3, acc);
    }
    for (; j < end; ++j) {
        int s0 = esrc[j];
        acc = fmaf(Hc[(size_t)s0 * 16 + ch16], dinv[s0], acc);
    }
    return fmaxf(fmaf(acc * dn, sc, sh), 0.f);
}

// variant A: bf16 hi/lo node-major (feeds next GEMM)
__global__ __launch_bounds__(256) void k_gather_bf(const float* __restrict__ H,
                                                   const int* __restrict__ rowstart,
                                                   const int* __restrict__ esrc,
                                                   const float* __restrict__ dinv,
                                                   const float* __restrict__ bnscale,
                                                   const float* __restrict__ bnshift,
                                                   ushort_t* __restrict__ Xh,
                                                   ushort_t* __restrict__ Xl) {
    int bid = blockIdx.x;
    int x8 = bid & 7;
    int rest = bid >> 3;                 // 0..1249
    int phase = (rest >= NB_G) ? 1 : 0;
    int nb = rest - phase * NB_G;
    int chunk = phase * 8 + x8;
    const float* Hc = H + (size_t)chunk * (N_NODES * 16);
    int sub = threadIdx.x >> 4;
    int ch16 = threadIdx.x & 15;
    float sc = bnscale[chunk * 16 + ch16];
    float sh = bnshift[chunk * 16 + ch16];
    int node0 = nb * NPB_G;
    #pragma unroll
    for (int b = 0; b < 5; ++b) {
        int node = node0 + b * 16 + sub;
        float o = gather_val(Hc, rowstart, esrc, dinv, sc, sh, node, ch16);
        ushort_t h = f2bf_rn(o);
        ushort_t l = f2bf_rn(o - bf2f(h));
        size_t oi = (size_t)node * HID + chunk * 16 + ch16;
        __builtin_nontemporal_store(h, Xh + oi);
        __builtin_nontemporal_store(l, Xl + oi);
    }
}

// variant B: fp32 chunk-major (last layer, feeds pool)
__global__ __launch_bounds__(256) void k_gather_f32(const float* __restrict__ H,
                                                    const int* __restrict__ rowstart,
                                                    const int* __restrict__ esrc,
                                                    const float* __restrict__ dinv,
                                                    const float* __restrict__ bnscale,
                                                    const float* __restrict__ bnshift,
                                                    float* __restrict__ X) {
    int bid = blockIdx.x;
    int x8 = bid & 7;
    int rest = bid >> 3;
    int phase = (rest >= NB_G) ? 1 : 0;
    int nb = rest - phase * NB_G;
    int chunk = phase * 8 + x8;
    const float* Hc = H + (size_t)chunk * (N_NODES * 16);
    float* Xc = X + (size_t)chunk * (N_NODES * 16);
    int sub = threadIdx.x >> 4;
    int ch16 = threadIdx.x & 15;
    float sc = bnscale[chunk * 16 + ch16];
    float sh = bnshift[chunk * 16 + ch16];
    int node0 = nb * NPB_G;
    #pragma unroll
    for (int b = 0; b < 5; ++b) {
        int node = node0 + b * 16 + sub;
        float o = gather_val(Hc, rowstart, esrc, dinv, sc, sh, node, ch16);
        __builtin_nontemporal_store(o, Xc + (size_t)node * 16 + ch16);
    }
}

// ---------------- segmented mean pool (X is chunk-major) ----------------
#define POOL_SPAN 25
__global__ __launch_bounds__(256) void k_pool(const float* __restrict__ X,
                                              const int* __restrict__ batch,
                                              float* __restrict__ pooled,
                                              int* __restrict__ cnt, int N) {
    int n0 = blockIdx.x * POOL_SPAN;
    int c = threadIdx.x;
    const float* Xc = X + (size_t)(c >> 4) * (N_NODES * 16) + (c & 15);
    int nend = min(n0 + POOL_SPAN, N);
    float acc = 0.f;
    int curg = batch[n0];
    int segcnt = 0;
    for (int n = n0; n < nend; ++n) {
        int g = batch[n];
        if (g != curg) {
            atomicAdd(&pooled[(size_t)curg * HID + c], acc);
            if (c == 0) atomicAdd(&cnt[curg], segcnt);
            acc = 0.f;
            segcnt = 0;
            curg = g;
        }
        acc += Xc[(size_t)n * 16];
        ++segcnt;
    }
    atomicAdd(&pooled[(size_t)curg * HID + c], acc);
    if (c == 0) atomicAdd(&cnt[curg], segcnt);
}

// ---------------- MLP head ----------------
__global__ __launch_bounds__(128) void k_mlp(const float* __restrict__ pooled,
                                             const int* __restrict__ cnt,
                                             const float* __restrict__ W1,
                                             const float* __restrict__ b1,
                                             const float* __restrict__ W2,
                                             const float* __restrict__ b2,
                                             float* __restrict__ out) {
    __shared__ float prow[HID];
    __shared__ float hred[2];
    int g = blockIdx.x;
    int j = threadIdx.x;
    prow[j] = pooled[(size_t)g * HID + j];
    prow[j + 128] = pooled[(size_t)g * HID + 128 + j];
    __syncthreads();
    float acc = 0.f;
    #pragma unroll 8
    for (int k = 0; k < HID; ++k) acc += prow[k] * W1[k * 128 + j];
    float inv = 1.0f / fmaxf((float)cnt[g], 1.0f);
    float h = fmaxf(acc * inv + b1[j], 0.f);
    float p = h * W2[j];
    #pragma unroll
    for (int off = 32; off > 0; off >>= 1) p += __shfl_down(p, off, 64);
    if ((j & 63) == 0) hred[j >> 6] = p;
    __syncthreads();
    if (j == 0) out[g] = hred[0] + hred[1] + b2[0];
}

extern "C" void kernel_launch(void* const* d_in, const int* in_sizes, int n_in,
                              void* d_out, int out_size, void* d_ws, size_t ws_size,
                              hipStream_t stream) {
    const float* x      = (const float*)d_in[0];
    const int*   ei     = (const int*)d_in[1];
    const int*   batch  = (const int*)d_in[2];
    const float* convW0 = (const float*)d_in[3];
    const float* convWs = (const float*)d_in[4];
    const float* convB  = (const float*)d_in[5];
    const float* gamma  = (const float*)d_in[6];
    const float* beta   = (const float*)d_in[7];
    const float* mean   = (const float*)d_in[8];
    const float* var    = (const float*)d_in[9];
    const float* lin1W  = (const float*)d_in[10];
    const float* lin1b  = (const float*)d_in[11];
    const float* lin2W  = (const float*)d_in[12];
    const float* lin2b  = (const float*)d_in[13];
    float* out = (float*)d_out;

    const int* src = ei;
    const int* dst = ei + N_EDGES;

    const int WTOT = 128 * 256 + 3 * 256 * 256; // 229376

    float* ws = (float*)d_ws;
    float* xbuf = ws;                                    // N*HID fp32 (layer3 out, chunk-major)
    float* hbuf = xbuf + (size_t)N_NODES * HID;          // N*HID fp32 (H, chunk-major)
    ushort_t* Ahb = (ushort_t*)(hbuf + (size_t)N_NODES * HID); // N*HID
    ushort_t* Alb = Ahb + (size_t)N_NODES * HID;         // N*HID
    ushort_t* WhT = Alb + (size_t)N_NODES * HID;         // WTOT
    ushort_t* WlT = WhT + WTOT;                          // WTOT
    float* dinv    = (float*)(WlT + WTOT);               // N
    float* pooled  = dinv + N_NODES;                     // G*HID
    float* bnscale = pooled + (size_t)N_GRAPHS * HID;    // 4*HID
    float* bnshift = bnscale + N_LAYERS * HID;           // 4*HID
    int*   cnt     = (int*)(bnshift + N_LAYERS * HID);   // G
    int*   degi    = cnt + N_GRAPHS;                     // N
    int*   rowstart= degi + N_NODES;                     // N+1
    int*   cursor  = rowstart + (N_NODES + 1);           // N
    int*   esrc    = cursor + N_NODES;                   // E

    hipMemsetAsync(degi, 0, (size_t)N_NODES * 4, stream);
    hipMemsetAsync(pooled, 0, (size_t)N_GRAPHS * HID * 4, stream);
    hipMemsetAsync(cnt, 0, (size_t)N_GRAPHS * 4, stream);

    // CSR build + norms
    k_deg<<<(N_EDGES + 255) / 256, 256, 0, stream>>>(dst, degi, N_EDGES);
    k_nodenorm<<<(N_NODES + 255) / 256, 256, 0, stream>>>(degi, dinv, N_NODES);
    k_scan<<<1, 1024, 0, stream>>>(degi, rowstart, cursor, N_NODES);
    k_fill<<<(N_EDGES + 255) / 256, 256, 0, stream>>>(src, dst, cursor, esrc, N_EDGES);

    // prep
    k_bnprep<<<N_LAYERS, 256, 0, stream>>>(gamma, beta, mean, var, convB, bnscale, bnshift);
    k_splitw<<<(WTOT + 255) / 256, 256, 0, stream>>>(convW0, convWs, WhT, WlT);
    k_splitx<<<(N_NODES * IN_DIM / 4 + 255) / 256, 256, 0, stream>>>(x, Ahb, Alb, N_NODES * IN_DIM / 4);

    dim3 gg((N_NODES + 127) / 128, HID / 128);
    for (int l = 0; l < N_LAYERS; ++l) {
        int K = (l == 0) ? IN_DIM : HID;
        size_t woff = (l == 0) ? 0 : (size_t)(32768 + (l - 1) * 65536);
        k_gemm<<<gg, 256, 0, stream>>>(Ahb, Alb, WhT + woff, WlT + woff, hbuf, K);
        if (l < N_LAYERS - 1)
            k_gather_bf<<<16 * NB_G, 256, 0, stream>>>(hbuf, rowstart, esrc, dinv,
                                                       bnscale + l * HID, bnshift + l * HID,
                                                       Ahb, Alb);
        else
            k_gather_f32<<<16 * NB_G, 256, 0, stream>>>(hbuf, rowstart, esrc, dinv,
                                                        bnscale + l * HID, bnshift + l * HID,
                                                        xbuf);
    }

    k_pool<<<(N_NODES + POOL_SPAN - 1) / POOL_SPAN, 256, 0, stream>>>(xbuf, batch, pooled, cnt, N_NODES);
    k_mlp<<<N_GRAPHS, 128, 0, stream>>>(pooled, cnt, lin1W, lin1b, lin2W, lin2b, out);
}

// Round 6
// 1029.947 us; speedup vs baseline: 1.0794x; 1.0794x over previous
//
#include <hip/hip_runtime.h>

#define N_NODES 50000
#define N_EDGES 800000
#define N_GRAPHS 2048
#define IN_DIM 128
#define HID 256
#define N_LAYERS 4
#define BN_EPS 1e-5f

typedef unsigned short ushort_t;
typedef __bf16 bf16x8 __attribute__((ext_vector_type(8)));
typedef float f32x4 __attribute__((ext_vector_type(4)));
typedef unsigned int u32x2 __attribute__((ext_vector_type(2)));

// ---- fp32 -> bf16 (round-to-nearest-even) helpers ----
__device__ __forceinline__ ushort_t f2bf_rn(float x) {
    unsigned int u = __float_as_uint(x);
    u += 0x7FFFu + ((u >> 16) & 1u);
    return (ushort_t)(u >> 16);
}
__device__ __forceinline__ float bf2f(ushort_t h) {
    return __uint_as_float(((unsigned int)h) << 16);
}

// ---- async global->LDS, 16B per lane ----
__device__ __forceinline__ void gl_lds16(const ushort_t* g, ushort_t* l) {
    __builtin_amdgcn_global_load_lds(
        (const __attribute__((address_space(1))) void*)g,
        (__attribute__((address_space(3))) void*)l, 16, 0, 0);
}

// ---------------- degree count ----------------
__global__ void k_deg(const int* __restrict__ dst, int* __restrict__ degi, int E) {
    int e = blockIdx.x * blockDim.x + threadIdx.x;
    if (e < E) atomicAdd(&degi[dst[e]], 1);
}

__global__ void k_nodenorm(const int* __restrict__ degi, float* __restrict__ dinv, int N) {
    int n = blockIdx.x * blockDim.x + threadIdx.x;
    if (n < N) {
        float d = 1.0f + (float)degi[n];
        dinv[n] = 1.0f / sqrtf(d);
    }
}

// ---------------- exclusive prefix scan (single block) ----------------
__global__ __launch_bounds__(1024) void k_scan(const int* __restrict__ degi,
                                               int* __restrict__ rowstart,
                                               int* __restrict__ cursor, int N) {
    __shared__ int part[1024];
    int t = threadIdx.x;
    int chunk = (N + 1023) / 1024;
    int b = t * chunk;
    int e = min(b + chunk, N);
    int s = 0;
    for (int i = b; i < e; ++i) s += degi[i];
    part[t] = s;
    __syncthreads();
    for (int off = 1; off < 1024; off <<= 1) {
        int v = (t >= off) ? part[t - off] : 0;
        __syncthreads();
        part[t] += v;
        __syncthreads();
    }
    int run = (t == 0) ? 0 : part[t - 1];
    for (int i = b; i < e; ++i) {
        rowstart[i] = run;
        cursor[i] = run;
        run += degi[i];
    }
    if (t == 1023) rowstart[N] = run;
}

// ---------------- CSR fill (src ids only; weights recomputed on the fly) ----------------
__global__ void k_fill(const int* __restrict__ src, const int* __restrict__ dst,
                       int* __restrict__ cursor, int* __restrict__ esrc, int E) {
    int e = blockIdx.x * blockDim.x + threadIdx.x;
    if (e >= E) return;
    int s = src[e], d = dst[e];
    int pos = atomicAdd(&cursor[d], 1);
    esrc[pos] = s;
}

// ---------------- split x -> bf16 hi/lo ----------------
__global__ __launch_bounds__(256) void k_splitx(const float* __restrict__ x,
                                                ushort_t* __restrict__ Ah,
                                                ushort_t* __restrict__ Al, int total4) {
    int i = blockIdx.x * blockDim.x + threadIdx.x;
    if (i >= total4) return;
    float4 v = ((const float4*)x)[i];
    ushort4 h, l;
    h.x = f2bf_rn(v.x); l.x = f2bf_rn(v.x - bf2f(h.x));
    h.y = f2bf_rn(v.y); l.y = f2bf_rn(v.y - bf2f(h.y));
    h.z = f2bf_rn(v.z); l.z = f2bf_rn(v.z - bf2f(h.z));
    h.w = f2bf_rn(v.w); l.w = f2bf_rn(v.w - bf2f(h.w));
    ((ushort4*)Ah)[i] = h;
    ((ushort4*)Al)[i] = l;
}

// ---------------- split + transpose weights -> [layer][n][k] bf16 hi/lo ----------------
__global__ void k_splitw(const float* __restrict__ W0, const float* __restrict__ Ws,
                         ushort_t* __restrict__ Wh, ushort_t* __restrict__ Wl) {
    int i = blockIdx.x * blockDim.x + threadIdx.x;
    const int total = 128 * 256 + 3 * 256 * 256;
    if (i >= total) return;
    float v;
    if (i < 32768) {
        int n = i >> 7, k = i & 127;
        v = W0[k * 256 + n];
    } else {
        int t = i - 32768;
        int l = t >> 16;
        int r = t & 65535;
        int n = r >> 8, k = r & 255;
        v = Ws[l * 65536 + k * 256 + n];
    }
    ushort_t h = f2bf_rn(v);
    Wh[i] = h;
    Wl[i] = f2bf_rn(v - bf2f(h));
}

// ---------------- MFMA split-bf16 GEMM: H = A[N x K] @ W[K x 256] ----------------
// 128x128 tile; 3-term split (AhWh + AhWl + AlWh); output H in CHUNK-MAJOR
// layout: H[chunk][node][16], chunk = col/16.
__global__ __launch_bounds__(256) void k_gemm(const ushort_t* __restrict__ Ah,
                                              const ushort_t* __restrict__ Al,
                                              const ushort_t* __restrict__ Wh,
                                              const ushort_t* __restrict__ Wl,
                                              float* __restrict__ H, int K) {
    __shared__ ushort_t sm[4 * 128 * 32]; // 32 KB: Ah|Al|Wh|Wl tiles
    ushort_t* tAh = sm;
    ushort_t* tAl = sm + 4096;
    ushort_t* tWh = sm + 8192;
    ushort_t* tWl = sm + 12288;

    int tid = threadIdx.x;
    int lane = tid & 63;
    int w = tid >> 6;
    int wrow = w & 1, wcol = w >> 1;
    int row0 = blockIdx.x * 128;
    int col0 = blockIdx.y * 128;

    const ushort_t* gsrc = (w == 0) ? Ah : (w == 1) ? Al : (w == 2) ? Wh : Wl;
    int rbase = (w < 2) ? row0 : col0;
    int rlimit = (w < 2) ? N_NODES : (col0 + 128);
    ushort_t* ldst = sm + w * 4096;
    int srow = lane >> 2;
    int sch = lane & 3;

    f32x4 acc[4][4] = {};
    int m = lane & 15, q = lane >> 4;

    for (int k0 = 0; k0 < K; k0 += 32) {
        #pragma unroll
        for (int i = 0; i < 8; ++i) {
            int r = i * 16 + srow;
            int grow = rbase + r;
            int gch = sch ^ (r & 3);
            if (grow < rlimit)
                gl_lds16(gsrc + (size_t)grow * K + k0 + gch * 8, ldst + i * 512);
        }
        __syncthreads();

        bf16x8 ahf[4], alf[4], whf[4], wlf[4];
        #pragma unroll
        for (int r = 0; r < 4; ++r) {
            int rr = wrow * 64 + r * 16 + m;
            int off = rr * 32 + ((q ^ (rr & 3)) << 3);
            ahf[r] = *(const bf16x8*)(tAh + off);
            alf[r] = *(const bf16x8*)(tAl + off);
        }
        #pragma unroll
        for (int c = 0; c < 4; ++c) {
            int nn = wcol * 64 + c * 16 + m;
            int off = nn * 32 + ((q ^ (nn & 3)) << 3);
            whf[c] = *(const bf16x8*)(tWh + off);
            wlf[c] = *(const bf16x8*)(tWl + off);
        }
        #pragma unroll
        for (int r = 0; r < 4; ++r)
            #pragma unroll
            for (int c = 0; c < 4; ++c) {
                acc[r][c] = __builtin_amdgcn_mfma_f32_16x16x32_bf16(ahf[r], whf[c], acc[r][c], 0, 0, 0);
                acc[r][c] = __builtin_amdgcn_mfma_f32_16x16x32_bf16(ahf[r], wlf[c], acc[r][c], 0, 0, 0);
                acc[r][c] = __builtin_amdgcn_mfma_f32_16x16x32_bf16(alf[r], whf[c], acc[r][c], 0, 0, 0);
            }
        __syncthreads();
    }

    #pragma unroll
    for (int r = 0; r < 4; ++r) {
        int mrow = row0 + wrow * 64 + r * 16 + (lane >> 4) * 4;
        #pragma unroll
        for (int c = 0; c < 4; ++c) {
            int n = col0 + wcol * 64 + c * 16 + (lane & 15);
            float* base = H + (size_t)(n >> 4) * (N_NODES * 16) + (n & 15);
            f32x4 v = acc[r][c];
            #pragma unroll
            for (int g = 0; g < 4; ++g)
                if (mrow + g < N_NODES)
                    base[(size_t)(mrow + g) * 16] = v[g];
        }
    }
}

// ---------------- BN prep (bias folded) ----------------
__global__ void k_bnprep(const float* __restrict__ gamma, const float* __restrict__ beta,
                         const float* __restrict__ mean, const float* __restrict__ var,
                         const float* __restrict__ bias,
                         float* __restrict__ scale, float* __restrict__ shift) {
    int l = blockIdx.x;
    int c = threadIdx.x;
    if (c < HID) {
        float s = gamma[l * HID + c] * rsqrtf(var[l * HID + c] + BN_EPS);
        scale[l * HID + c] = s;
        shift[l * HID + c] = beta[l * HID + c] + (bias[l * HID + c] - mean[l * HID + c]) * s;
    }
}

// ---------------- chunked gather, hybrid: XCD-affine 16-ch slices, float4 loads ----------------
// H chunk-major [16][N][16]. 4 threads per node (each owns a 4-ch quad, 64B/node-edge
// across the 4 lanes). chunk = (blockIdx%8) + 8*phase for XCD L2 affinity.
#define GNB 782  // ceil(50000/64) node-blocks per chunk

__device__ __forceinline__ float4 gather_quad(const float* __restrict__ Hc,
                                              const int* __restrict__ rowstart,
                                              const int* __restrict__ esrc,
                                              const float* __restrict__ dinv,
                                              float4 sc, float4 sh, int node, int q4) {
    int beg = rowstart[node];
    int end = rowstart[node + 1];
    float dn = dinv[node];
    float4 h = *(const float4*)(Hc + (size_t)node * 16 + q4);
    float4 acc;
    acc.x = h.x * dn; acc.y = h.y * dn; acc.z = h.z * dn; acc.w = h.w * dn;
    int j = beg;
    for (; j + 3 < end; j += 4) {
        int s0 = esrc[j], s1 = esrc[j + 1], s2 = esrc[j + 2], s3 = esrc[j + 3];
        float w0 = dinv[s0], w1 = dinv[s1], w2 = dinv[s2], w3 = dinv[s3];
        float4 v0 = *(const float4*)(Hc + (size_t)s0 * 16 + q4);
        float4 v1 = *(const float4*)(Hc + (size_t)s1 * 16 + q4);
        float4 v2 = *(const float4*)(Hc + (size_t)s2 * 16 + q4);
        float4 v3 = *(const float4*)(Hc + (size_t)s3 * 16 + q4);
        acc.x = fmaf(v0.x, w0, acc.x); acc.y = fmaf(v0.y, w0, acc.y);
        acc.z = fmaf(v0.z, w0, acc.z); acc.w = fmaf(v0.w, w0, acc.w);
        acc.x = fmaf(v1.x, w1, acc.x); acc.y = fmaf(v1.y, w1, acc.y);
        acc.z = fmaf(v1.z, w1, acc.z); acc.w = fmaf(v1.w, w1, acc.w);
        acc.x = fmaf(v2.x, w2, acc.x); acc.y = fmaf(v2.y, w2, acc.y);
        acc.z = fmaf(v2.z, w2, acc.z); acc.w = fmaf(v2.w, w2, acc.w);
        acc.x = fmaf(v3.x, w3, acc.x); acc.y = fmaf(v3.y, w3, acc.y);
        acc.z = fmaf(v3.z, w3, acc.z); acc.w = fmaf(v3.w, w3, acc.w);
    }
    for (; j < end; ++j) {
        int s0 = esrc[j];
        float w0 = dinv[s0];
        float4 v0 = *(const float4*)(Hc + (size_t)s0 * 16 + q4);
        acc.x = fmaf(v0.x, w0, acc.x); acc.y = fmaf(v0.y, w0, acc.y);
        acc.z = fmaf(v0.z, w0, acc.z); acc.w = fmaf(v0.w, w0, acc.w);
    }
    float4 o;
    o.x = fmaxf(fmaf(acc.x * dn, sc.x, sh.x), 0.f);
    o.y = fmaxf(fmaf(acc.y * dn, sc.y, sh.y), 0.f);
    o.z = fmaxf(fmaf(acc.z * dn, sc.z, sh.z), 0.f);
    o.w = fmaxf(fmaf(acc.w * dn, sc.w, sh.w), 0.f);
    return o;
}

// variant A: bf16 hi/lo node-major (feeds next GEMM)
__global__ __launch_bounds__(256) void k_gather_bf(const float* __restrict__ H,
                                                   const int* __restrict__ rowstart,
                                                   const int* __restrict__ esrc,
                                                   const float* __restrict__ dinv,
                                                   const float* __restrict__ bnscale,
                                                   const float* __restrict__ bnshift,
                                                   ushort_t* __restrict__ Xh,
                                                   ushort_t* __restrict__ Xl) {
    int bid = blockIdx.x;
    int x8 = bid & 7;
    int rest = bid >> 3;
    int phase = (rest >= GNB) ? 1 : 0;
    int nb = rest - phase * GNB;
    int chunk = phase * 8 + x8;
    const float* Hc = H + (size_t)chunk * (N_NODES * 16);
    int node = nb * 64 + (threadIdx.x >> 2);
    if (node >= N_NODES) return;
    int q4 = (threadIdx.x & 3) * 4;
    float4 sc = *(const float4*)(bnscale + chunk * 16 + q4);
    float4 sh = *(const float4*)(bnshift + chunk * 16 + q4);
    float4 o = gather_quad(Hc, rowstart, esrc, dinv, sc, sh, node, q4);
    ushort4 h, l;
    h.x = f2bf_rn(o.x); l.x = f2bf_rn(o.x - bf2f(h.x));
    h.y = f2bf_rn(o.y); l.y = f2bf_rn(o.y - bf2f(h.y));
    h.z = f2bf_rn(o.z); l.z = f2bf_rn(o.z - bf2f(h.z));
    h.w = f2bf_rn(o.w); l.w = f2bf_rn(o.w - bf2f(h.w));
    size_t oi = (size_t)node * HID + chunk * 16 + q4;
    u32x2 hv, lv;
    hv.x = ((unsigned int)h.y << 16) | h.x;
    hv.y = ((unsigned int)h.w << 16) | h.z;
    lv.x = ((unsigned int)l.y << 16) | l.x;
    lv.y = ((unsigned int)l.w << 16) | l.z;
    __builtin_nontemporal_store(hv, (u32x2*)(Xh + oi));
    __builtin_nontemporal_store(lv, (u32x2*)(Xl + oi));
}

// variant B: fp32 chunk-major (last layer, feeds pool)
__global__ __launch_bounds__(256) void k_gather_f32(const float* __restrict__ H,
                                                    const int* __restrict__ rowstart,
                                                    const int* __restrict__ esrc,
                                                    const float* __restrict__ dinv,
                                                    const float* __restrict__ bnscale,
                                                    const float* __restrict__ bnshift,
                                                    float* __restrict__ X) {
    int bid = blockIdx.x;
    int x8 = bid & 7;
    int rest = bid >> 3;
    int phase = (rest >= GNB) ? 1 : 0;
    int nb = rest - phase * GNB;
    int chunk = phase * 8 + x8;
    const float* Hc = H + (size_t)chunk * (N_NODES * 16);
    float* Xc = X + (size_t)chunk * (N_NODES * 16);
    int node = nb * 64 + (threadIdx.x >> 2);
    if (node >= N_NODES) return;
    int q4 = (threadIdx.x & 3) * 4;
    float4 sc = *(const float4*)(bnscale + chunk * 16 + q4);
    float4 sh = *(const float4*)(bnshift + chunk * 16 + q4);
    float4 o = gather_quad(Hc, rowstart, esrc, dinv, sc, sh, node, q4);
    f32x4 ov;
    ov.x = o.x; ov.y = o.y; ov.z = o.z; ov.w = o.w;
    __builtin_nontemporal_store(ov, (f32x4*)(Xc + (size_t)node * 16 + q4));
}

// ---------------- segmented mean pool (X is chunk-major) ----------------
#define POOL_SPAN 25
__global__ __launch_bounds__(256) void k_pool(const float* __restrict__ X,
                                              const int* __restrict__ batch,
                                              float* __restrict__ pooled,
                                              int* __restrict__ cnt, int N) {
    int n0 = blockIdx.x * POOL_SPAN;
    int c = threadIdx.x;
    const float* Xc = X + (size_t)(c >> 4) * (N_NODES * 16) + (c & 15);
    int nend = min(n0 + POOL_SPAN, N);
    float acc = 0.f;
    int curg = batch[n0];
    int segcnt = 0;
    for (int n = n0; n < nend; ++n) {
        int g = batch[n];
        if (g != curg) {
            atomicAdd(&pooled[(size_t)curg * HID + c], acc);
            if (c == 0) atomicAdd(&cnt[curg], segcnt);
            acc = 0.f;
            segcnt = 0;
            curg = g;
        }
        acc += Xc[(size_t)n * 16];
        ++segcnt;
    }
    atomicAdd(&pooled[(size_t)curg * HID + c], acc);
    if (c == 0) atomicAdd(&cnt[curg], segcnt);
}

// ---------------- MLP head ----------------
__global__ __launch_bounds__(128) void k_mlp(const float* __restrict__ pooled,
                                             const int* __restrict__ cnt,
                                             const float* __restrict__ W1,
                                             const float* __restrict__ b1,
                                             const float* __restrict__ W2,
                                             const float* __restrict__ b2,
                                             float* __restrict__ out) {
    __shared__ float prow[HID];
    __shared__ float hred[2];
    int g = blockIdx.x;
    int j = threadIdx.x;
    prow[j] = pooled[(size_t)g * HID + j];
    prow[j + 128] = pooled[(size_t)g * HID + 128 + j];
    __syncthreads();
    float acc = 0.f;
    #pragma unroll 8
    for (int k = 0; k < HID; ++k) acc += prow[k] * W1[k * 128 + j];
    float inv = 1.0f / fmaxf((float)cnt[g], 1.0f);
    float h = fmaxf(acc * inv + b1[j], 0.f);
    float p = h * W2[j];
    #pragma unroll
    for (int off = 32; off > 0; off >>= 1) p += __shfl_down(p, off, 64);
    if ((j & 63) == 0) hred[j >> 6] = p;
    __syncthreads();
    if (j == 0) out[g] = hred[0] + hred[1] + b2[0];
}

extern "C" void kernel_launch(void* const* d_in, const int* in_sizes, int n_in,
                              void* d_out, int out_size, void* d_ws, size_t ws_size,
                              hipStream_t stream) {
    const float* x      = (const float*)d_in[0];
    const int*   ei     = (const int*)d_in[1];
    const int*   batch  = (const int*)d_in[2];
    const float* convW0 = (const float*)d_in[3];
    const float* convWs = (const float*)d_in[4];
    const float* convB  = (const float*)d_in[5];
    const float* gamma  = (const float*)d_in[6];
    const float* beta   = (const float*)d_in[7];
    const float* mean   = (const float*)d_in[8];
    const float* var    = (const float*)d_in[9];
    const float* lin1W  = (const float*)d_in[10];
    const float* lin1b  = (const float*)d_in[11];
    const float* lin2W  = (const float*)d_in[12];
    const float* lin2b  = (const float*)d_in[13];
    float* out = (float*)d_out;

    const int* src = ei;
    const int* dst = ei + N_EDGES;

    const int WTOT = 128 * 256 + 3 * 256 * 256; // 229376

    float* ws = (float*)d_ws;
    float* xbuf = ws;                                    // N*HID fp32 (layer3 out, chunk-major)
    float* hbuf = xbuf + (size_t)N_NODES * HID;          // N*HID fp32 (H, chunk-major)
    ushort_t* Ahb = (ushort_t*)(hbuf + (size_t)N_NODES * HID); // N*HID
    ushort_t* Alb = Ahb + (size_t)N_NODES * HID;         // N*HID
    ushort_t* WhT = Alb + (size_t)N_NODES * HID;         // WTOT
    ushort_t* WlT = WhT + WTOT;                          // WTOT
    float* dinv    = (float*)(WlT + WTOT);               // N
    float* pooled  = dinv + N_NODES;                     // G*HID
    float* bnscale = pooled + (size_t)N_GRAPHS * HID;    // 4*HID
    float* bnshift = bnscale + N_LAYERS * HID;           // 4*HID
    int*   cnt     = (int*)(bnshift + N_LAYERS * HID);   // G
    int*   degi    = cnt + N_GRAPHS;                     // N
    int*   rowstart= degi + N_NODES;                     // N+1
    int*   cursor  = rowstart + (N_NODES + 1);           // N
    int*   esrc    = cursor + N_NODES;                   // E

    hipMemsetAsync(degi, 0, (size_t)N_NODES * 4, stream);
    hipMemsetAsync(pooled, 0, (size_t)N_GRAPHS * HID * 4, stream);
    hipMemsetAsync(cnt, 0, (size_t)N_GRAPHS * 4, stream);

    // CSR build + norms
    k_deg<<<(N_EDGES + 255) / 256, 256, 0, stream>>>(dst, degi, N_EDGES);
    k_nodenorm<<<(N_NODES + 255) / 256, 256, 0, stream>>>(degi, dinv, N_NODES);
    k_scan<<<1, 1024, 0, stream>>>(degi, rowstart, cursor, N_NODES);
    k_fill<<<(N_EDGES + 255) / 256, 256, 0, stream>>>(src, dst, cursor, esrc, N_EDGES);

    // prep
    k_bnprep<<<N_LAYERS, 256, 0, stream>>>(gamma, beta, mean, var, convB, bnscale, bnshift);
    k_splitw<<<(WTOT + 255) / 256, 256, 0, stream>>>(convW0, convWs, WhT, WlT);
    k_splitx<<<(N_NODES * IN_DIM / 4 + 255) / 256, 256, 0, stream>>>(x, Ahb, Alb, N_NODES * IN_DIM / 4);

    dim3 gg((N_NODES + 127) / 128, HID / 128);
    for (int l = 0; l < N_LAYERS; ++l) {
        int K = (l == 0) ? IN_DIM : HID;
        size_t woff = (l == 0) ? 0 : (size_t)(32768 + (l - 1) * 65536);
        k_gemm<<<gg, 256, 0, stream>>>(Ahb, Alb, WhT + woff, WlT + woff, hbuf, K);
        if (l < N_LAYERS - 1)
            k_gather_bf<<<16 * GNB, 256, 0, stream>>>(hbuf, rowstart, esrc, dinv,
                                                      bnscale + l * HID, bnshift + l * HID,
                                                      Ahb, Alb);
        else
            k_gather_f32<<<16 * GNB, 256, 0, stream>>>(hbuf, rowstart, esrc, dinv,
                                                       bnscale + l * HID, bnshift + l * HID,
                                                       xbuf);
    }

    k_pool<<<(N_NODES + POOL_SPAN - 1) / POOL_SPAN, 256, 0, stream>>>(xbuf, batch, pooled, cnt, N_NODES);
    k_mlp<<<N_GRAPHS, 128, 0, stream>>>(pooled, cnt, lin1W, lin1b, lin2W, lin2b, out);
}

// Round 7
// 892.603 us; speedup vs baseline: 1.2455x; 1.1539x over previous
//
#include <hip/hip_runtime.h>

#define N_NODES 50000
#define N_EDGES 800000
#define N_GRAPHS 2048
#define IN_DIM 128
#define HID 256
#define N_LAYERS 4
#define BN_EPS 1e-5f

typedef unsigned short ushort_t;
typedef __bf16 bf16x8 __attribute__((ext_vector_type(8)));
typedef float f32x4 __attribute__((ext_vector_type(4)));
typedef unsigned int u32x2 __attribute__((ext_vector_type(2)));

// ---- fp32 -> bf16 (round-to-nearest-even) helpers ----
__device__ __forceinline__ ushort_t f2bf_rn(float x) {
    unsigned int u = __float_as_uint(x);
    u += 0x7FFFu + ((u >> 16) & 1u);
    return (ushort_t)(u >> 16);
}
__device__ __forceinline__ float bf2f(ushort_t h) {
    return __uint_as_float(((unsigned int)h) << 16);
}

// ---- async global->LDS, 16B per lane ----
__device__ __forceinline__ void gl_lds16(const ushort_t* g, ushort_t* l) {
    __builtin_amdgcn_global_load_lds(
        (const __attribute__((address_space(1))) void*)g,
        (__attribute__((address_space(3))) void*)l, 16, 0, 0);
}

// ---------------- degree count ----------------
__global__ void k_deg(const int* __restrict__ dst, int* __restrict__ degi, int E) {
    int e = blockIdx.x * blockDim.x + threadIdx.x;
    if (e < E) atomicAdd(&degi[dst[e]], 1);
}

__global__ void k_nodenorm(const int* __restrict__ degi, float* __restrict__ dinv,
                           float* __restrict__ selfn, int N) {
    int n = blockIdx.x * blockDim.x + threadIdx.x;
    if (n < N) {
        float d = 1.0f + (float)degi[n];
        dinv[n] = 1.0f / sqrtf(d);
        selfn[n] = 1.0f / d;
    }
}

// ---------------- exclusive prefix scan (single block) ----------------
__global__ __launch_bounds__(1024) void k_scan(const int* __restrict__ degi,
                                               int* __restrict__ rowstart,
                                               int* __restrict__ cursor, int N) {
    __shared__ int part[1024];
    int t = threadIdx.x;
    int chunk = (N + 1023) / 1024;
    int b = t * chunk;
    int e = min(b + chunk, N);
    int s = 0;
    for (int i = b; i < e; ++i) s += degi[i];
    part[t] = s;
    __syncthreads();
    for (int off = 1; off < 1024; off <<= 1) {
        int v = (t >= off) ? part[t - off] : 0;
        __syncthreads();
        part[t] += v;
        __syncthreads();
    }
    int run = (t == 0) ? 0 : part[t - 1];
    for (int i = b; i < e; ++i) {
        rowstart[i] = run;
        cursor[i] = run;
        run += degi[i];
    }
    if (t == 1023) rowstart[N] = run;
}

// ---------------- CSR fill: pack {src, weight} per edge ----------------
__global__ void k_fill(const int* __restrict__ src, const int* __restrict__ dst,
                       const float* __restrict__ dinv, int* __restrict__ cursor,
                       int2* __restrict__ edata, int E) {
    int e = blockIdx.x * blockDim.x + threadIdx.x;
    if (e >= E) return;
    int s = src[e], d = dst[e];
    int pos = atomicAdd(&cursor[d], 1);
    int2 v;
    v.x = s;
    v.y = __float_as_int(dinv[s] * dinv[d]);
    edata[pos] = v;
}

// ---------------- split x -> bf16 hi/lo ----------------
__global__ __launch_bounds__(256) void k_splitx(const float* __restrict__ x,
                                                ushort_t* __restrict__ Ah,
                                                ushort_t* __restrict__ Al, int total4) {
    int i = blockIdx.x * blockDim.x + threadIdx.x;
    if (i >= total4) return;
    float4 v = ((const float4*)x)[i];
    ushort4 h, l;
    h.x = f2bf_rn(v.x); l.x = f2bf_rn(v.x - bf2f(h.x));
    h.y = f2bf_rn(v.y); l.y = f2bf_rn(v.y - bf2f(h.y));
    h.z = f2bf_rn(v.z); l.z = f2bf_rn(v.z - bf2f(h.z));
    h.w = f2bf_rn(v.w); l.w = f2bf_rn(v.w - bf2f(h.w));
    ((ushort4*)Ah)[i] = h;
    ((ushort4*)Al)[i] = l;
}

// ---------------- split + transpose weights -> [layer][n][k] bf16 hi/lo ----------------
__global__ void k_splitw(const float* __restrict__ W0, const float* __restrict__ Ws,
                         ushort_t* __restrict__ Wh, ushort_t* __restrict__ Wl) {
    int i = blockIdx.x * blockDim.x + threadIdx.x;
    const int total = 128 * 256 + 3 * 256 * 256;
    if (i >= total) return;
    float v;
    if (i < 32768) {
        int n = i >> 7, k = i & 127;
        v = W0[k * 256 + n];
    } else {
        int t = i - 32768;
        int l = t >> 16;
        int r = t & 65535;
        int n = r >> 8, k = r & 255;
        v = Ws[l * 65536 + k * 256 + n];
    }
    ushort_t h = f2bf_rn(v);
    Wh[i] = h;
    Wl[i] = f2bf_rn(v - bf2f(h));
}

// ---------------- MFMA split-bf16 GEMM: H = A[N x K] @ W[K x 256] ----------------
// 128x128 tile; 3-term split (AhWh + AhWl + AlWh); output H in CHUNK-MAJOR
// layout: H[chunk][node][16], chunk = col/16.
__global__ __launch_bounds__(256) void k_gemm(const ushort_t* __restrict__ Ah,
                                              const ushort_t* __restrict__ Al,
                                              const ushort_t* __restrict__ Wh,
                                              const ushort_t* __restrict__ Wl,
                                              float* __restrict__ H, int K) {
    __shared__ ushort_t sm[4 * 128 * 32]; // 32 KB: Ah|Al|Wh|Wl tiles
    ushort_t* tAh = sm;
    ushort_t* tAl = sm + 4096;
    ushort_t* tWh = sm + 8192;
    ushort_t* tWl = sm + 12288;

    int tid = threadIdx.x;
    int lane = tid & 63;
    int w = tid >> 6;
    int wrow = w & 1, wcol = w >> 1;
    int row0 = blockIdx.x * 128;
    int col0 = blockIdx.y * 128;

    const ushort_t* gsrc = (w == 0) ? Ah : (w == 1) ? Al : (w == 2) ? Wh : Wl;
    int rbase = (w < 2) ? row0 : col0;
    int rlimit = (w < 2) ? N_NODES : (col0 + 128);
    ushort_t* ldst = sm + w * 4096;
    int srow = lane >> 2;
    int sch = lane & 3;

    f32x4 acc[4][4] = {};
    int m = lane & 15, q = lane >> 4;

    for (int k0 = 0; k0 < K; k0 += 32) {
        #pragma unroll
        for (int i = 0; i < 8; ++i) {
            int r = i * 16 + srow;
            int grow = rbase + r;
            int gch = sch ^ (r & 3);
            if (grow < rlimit)
                gl_lds16(gsrc + (size_t)grow * K + k0 + gch * 8, ldst + i * 512);
        }
        __syncthreads();

        bf16x8 ahf[4], alf[4], whf[4], wlf[4];
        #pragma unroll
        for (int r = 0; r < 4; ++r) {
            int rr = wrow * 64 + r * 16 + m;
            int off = rr * 32 + ((q ^ (rr & 3)) << 3);
            ahf[r] = *(const bf16x8*)(tAh + off);
            alf[r] = *(const bf16x8*)(tAl + off);
        }
        #pragma unroll
        for (int c = 0; c < 4; ++c) {
            int nn = wcol * 64 + c * 16 + m;
            int off = nn * 32 + ((q ^ (nn & 3)) << 3);
            whf[c] = *(const bf16x8*)(tWh + off);
            wlf[c] = *(const bf16x8*)(tWl + off);
        }
        #pragma unroll
        for (int r = 0; r < 4; ++r)
            #pragma unroll
            for (int c = 0; c < 4; ++c) {
                acc[r][c] = __builtin_amdgcn_mfma_f32_16x16x32_bf16(ahf[r], whf[c], acc[r][c], 0, 0, 0);
                acc[r][c] = __builtin_amdgcn_mfma_f32_16x16x32_bf16(ahf[r], wlf[c], acc[r][c], 0, 0, 0);
                acc[r][c] = __builtin_amdgcn_mfma_f32_16x16x32_bf16(alf[r], whf[c], acc[r][c], 0, 0, 0);
            }
        __syncthreads();
    }

    #pragma unroll
    for (int r = 0; r < 4; ++r) {
        int mrow = row0 + wrow * 64 + r * 16 + (lane >> 4) * 4;
        #pragma unroll
        for (int c = 0; c < 4; ++c) {
            int n = col0 + wcol * 64 + c * 16 + (lane & 15);
            float* base = H + (size_t)(n >> 4) * (N_NODES * 16) + (n & 15);
            f32x4 v = acc[r][c];
            #pragma unroll
            for (int g = 0; g < 4; ++g)
                if (mrow + g < N_NODES)
                    base[(size_t)(mrow + g) * 16] = v[g];
        }
    }
}

// ---------------- BN prep (bias folded) ----------------
__global__ void k_bnprep(const float* __restrict__ gamma, const float* __restrict__ beta,
                         const float* __restrict__ mean, const float* __restrict__ var,
                         const float* __restrict__ bias,
                         float* __restrict__ scale, float* __restrict__ shift) {
    int l = blockIdx.x;
    int c = threadIdx.x;
    if (c < HID) {
        float s = gamma[l * HID + c] * rsqrtf(var[l * HID + c] + BN_EPS);
        scale[l * HID + c] = s;
        shift[l * HID + c] = beta[l * HID + c] + (bias[l * HID + c] - mean[l * HID + c]) * s;
    }
}

// ---------------- chunked gather: XCD-affine 16-ch slices, packed edges, deep unroll ----------------
// H chunk-major [16][N][16]. 4 threads per node (each owns a 4-ch quad).
// edata[j] = {src, weight_bits}; self term via selfn. chunk = (blockIdx%8)+8*phase.
#define GNB 782  // ceil(50000/64) node-blocks per chunk

#define EDGE_FMA(E, V) \
    { float wght = __int_as_float(E.y); \
      acc.x = fmaf(V.x, wght, acc.x); acc.y = fmaf(V.y, wght, acc.y); \
      acc.z = fmaf(V.z, wght, acc.z); acc.w = fmaf(V.w, wght, acc.w); }

__device__ __forceinline__ float4 gather_quad(const float* __restrict__ Hc,
                                              const int* __restrict__ rowstart,
                                              const int2* __restrict__ edata,
                                              const float* __restrict__ selfn,
                                              float4 sc, float4 sh, int node, int q4) {
    int beg = rowstart[node];
    int end = rowstart[node + 1];
    float sn = selfn[node];
    float4 h = *(const float4*)(Hc + (size_t)node * 16 + q4);
    float4 acc;
    acc.x = h.x * sn; acc.y = h.y * sn; acc.z = h.z * sn; acc.w = h.w * sn;
    int j = beg;
    for (; j + 7 < end; j += 8) {
        int2 e0 = edata[j], e1 = edata[j + 1], e2 = edata[j + 2], e3 = edata[j + 3];
        int2 e4 = edata[j + 4], e5 = edata[j + 5], e6 = edata[j + 6], e7 = edata[j + 7];
        float4 v0 = *(const float4*)(Hc + (size_t)e0.x * 16 + q4);
        float4 v1 = *(const float4*)(Hc + (size_t)e1.x * 16 + q4);
        float4 v2 = *(const float4*)(Hc + (size_t)e2.x * 16 + q4);
        float4 v3 = *(const float4*)(Hc + (size_t)e3.x * 16 + q4);
        float4 v4 = *(const float4*)(Hc + (size_t)e4.x * 16 + q4);
        float4 v5 = *(const float4*)(Hc + (size_t)e5.x * 16 + q4);
        float4 v6 = *(const float4*)(Hc + (size_t)e6.x * 16 + q4);
        float4 v7 = *(const float4*)(Hc + (size_t)e7.x * 16 + q4);
        EDGE_FMA(e0, v0) EDGE_FMA(e1, v1) EDGE_FMA(e2, v2) EDGE_FMA(e3, v3)
        EDGE_FMA(e4, v4) EDGE_FMA(e5, v5) EDGE_FMA(e6, v6) EDGE_FMA(e7, v7)
    }
    for (; j + 3 < end; j += 4) {
        int2 e0 = edata[j], e1 = edata[j + 1], e2 = edata[j + 2], e3 = edata[j + 3];
        float4 v0 = *(const float4*)(Hc + (size_t)e0.x * 16 + q4);
        float4 v1 = *(const float4*)(Hc + (size_t)e1.x * 16 + q4);
        float4 v2 = *(const float4*)(Hc + (size_t)e2.x * 16 + q4);
        float4 v3 = *(const float4*)(Hc + (size_t)e3.x * 16 + q4);
        EDGE_FMA(e0, v0) EDGE_FMA(e1, v1) EDGE_FMA(e2, v2) EDGE_FMA(e3, v3)
    }
    for (; j < end; ++j) {
        int2 e0 = edata[j];
        float4 v0 = *(const float4*)(Hc + (size_t)e0.x * 16 + q4);
        EDGE_FMA(e0, v0)
    }
    float4 o;
    o.x = fmaxf(fmaf(acc.x, sc.x, sh.x), 0.f);
    o.y = fmaxf(fmaf(acc.y, sc.y, sh.y), 0.f);
    o.z = fmaxf(fmaf(acc.z, sc.z, sh.z), 0.f);
    o.w = fmaxf(fmaf(acc.w, sc.w, sh.w), 0.f);
    return o;
}

// variant A: bf16 hi/lo node-major (feeds next GEMM)
__global__ __launch_bounds__(256) void k_gather_bf(const float* __restrict__ H,
                                                   const int* __restrict__ rowstart,
                                                   const int2* __restrict__ edata,
                                                   const float* __restrict__ selfn,
                                                   const float* __restrict__ bnscale,
                                                   const float* __restrict__ bnshift,
                                                   ushort_t* __restrict__ Xh,
                                                   ushort_t* __restrict__ Xl) {
    int bid = blockIdx.x;
    int x8 = bid & 7;
    int rest = bid >> 3;
    int phase = (rest >= GNB) ? 1 : 0;
    int nb = rest - phase * GNB;
    int chunk = phase * 8 + x8;
    const float* Hc = H + (size_t)chunk * (N_NODES * 16);
    int node = nb * 64 + (threadIdx.x >> 2);
    if (node >= N_NODES) return;
    int q4 = (threadIdx.x & 3) * 4;
    float4 sc = *(const float4*)(bnscale + chunk * 16 + q4);
    float4 sh = *(const float4*)(bnshift + chunk * 16 + q4);
    float4 o = gather_quad(Hc, rowstart, edata, selfn, sc, sh, node, q4);
    ushort4 h, l;
    h.x = f2bf_rn(o.x); l.x = f2bf_rn(o.x - bf2f(h.x));
    h.y = f2bf_rn(o.y); l.y = f2bf_rn(o.y - bf2f(h.y));
    h.z = f2bf_rn(o.z); l.z = f2bf_rn(o.z - bf2f(h.z));
    h.w = f2bf_rn(o.w); l.w = f2bf_rn(o.w - bf2f(h.w));
    size_t oi = (size_t)node * HID + chunk * 16 + q4;
    u32x2 hv, lv;
    hv.x = ((unsigned int)h.y << 16) | h.x;
    hv.y = ((unsigned int)h.w << 16) | h.z;
    lv.x = ((unsigned int)l.y << 16) | l.x;
    lv.y = ((unsigned int)l.w << 16) | l.z;
    __builtin_nontemporal_store(hv, (u32x2*)(Xh + oi));
    __builtin_nontemporal_store(lv, (u32x2*)(Xl + oi));
}

// variant B: fp32 chunk-major (last layer, feeds pool)
__global__ __launch_bounds__(256) void k_gather_f32(const float* __restrict__ H,
                                                    const int* __restrict__ rowstart,
                                                    const int2* __restrict__ edata,
                                                    const float* __restrict__ selfn,
                                                    const float* __restrict__ bnscale,
                                                    const float* __restrict__ bnshift,
                                                    float* __restrict__ X) {
    int bid = blockIdx.x;
    int x8 = bid & 7;
    int rest = bid >> 3;
    int phase = (rest >= GNB) ? 1 : 0;
    int nb = rest - phase * GNB;
    int chunk = phase * 8 + x8;
    const float* Hc = H + (size_t)chunk * (N_NODES * 16);
    float* Xc = X + (size_t)chunk * (N_NODES * 16);
    int node = nb * 64 + (threadIdx.x >> 2);
    if (node >= N_NODES) return;
    int q4 = (threadIdx.x & 3) * 4;
    float4 sc = *(const float4*)(bnscale + chunk * 16 + q4);
    float4 sh = *(const float4*)(bnshift + chunk * 16 + q4);
    float4 o = gather_quad(Hc, rowstart, edata, selfn, sc, sh, node, q4);
    f32x4 ov;
    ov.x = o.x; ov.y = o.y; ov.z = o.z; ov.w = o.w;
    __builtin_nontemporal_store(ov, (f32x4*)(Xc + (size_t)node * 16 + q4));
}

// ---------------- segmented mean pool (X is chunk-major) ----------------
#define POOL_SPAN 25
__global__ __launch_bounds__(256) void k_pool(const float* __restrict__ X,
                                              const int* __restrict__ batch,
                                              float* __restrict__ pooled,
                                              int* __restrict__ cnt, int N) {
    int n0 = blockIdx.x * POOL_SPAN;
    int c = threadIdx.x;
    const float* Xc = X + (size_t)(c >> 4) * (N_NODES * 16) + (c & 15);
    int nend = min(n0 + POOL_SPAN, N);
    float acc = 0.f;
    int curg = batch[n0];
    int segcnt = 0;
    for (int n = n0; n < nend; ++n) {
        int g = batch[n];
        if (g != curg) {
            atomicAdd(&pooled[(size_t)curg * HID + c], acc);
            if (c == 0) atomicAdd(&cnt[curg], segcnt);
            acc = 0.f;
            segcnt = 0;
            curg = g;
        }
        acc += Xc[(size_t)n * 16];
        ++segcnt;
    }
    atomicAdd(&pooled[(size_t)curg * HID + c], acc);
    if (c == 0) atomicAdd(&cnt[curg], segcnt);
}

// ---------------- MLP head ----------------
__global__ __launch_bounds__(128) void k_mlp(const float* __restrict__ pooled,
                                             const int* __restrict__ cnt,
                                             const float* __restrict__ W1,
                                             const float* __restrict__ b1,
                                             const float* __restrict__ W2,
                                             const float* __restrict__ b2,
                                             float* __restrict__ out) {
    __shared__ float prow[HID];
    __shared__ float hred[2];
    int g = blockIdx.x;
    int j = threadIdx.x;
    prow[j] = pooled[(size_t)g * HID + j];
    prow[j + 128] = pooled[(size_t)g * HID + 128 + j];
    __syncthreads();
    float acc = 0.f;
    #pragma unroll 8
    for (int k = 0; k < HID; ++k) acc += prow[k] * W1[k * 128 + j];
    float inv = 1.0f / fmaxf((float)cnt[g], 1.0f);
    float h = fmaxf(acc * inv + b1[j], 0.f);
    float p = h * W2[j];
    #pragma unroll
    for (int off = 32; off > 0; off >>= 1) p += __shfl_down(p, off, 64);
    if ((j & 63) == 0) hred[j >> 6] = p;
    __syncthreads();
    if (j == 0) out[g] = hred[0] + hred[1] + b2[0];
}

extern "C" void kernel_launch(void* const* d_in, const int* in_sizes, int n_in,
                              void* d_out, int out_size, void* d_ws, size_t ws_size,
                              hipStream_t stream) {
    const float* x      = (const float*)d_in[0];
    const int*   ei     = (const int*)d_in[1];
    const int*   batch  = (const int*)d_in[2];
    const float* convW0 = (const float*)d_in[3];
    const float* convWs = (const float*)d_in[4];
    const float* convB  = (const float*)d_in[5];
    const float* gamma  = (const float*)d_in[6];
    const float* beta   = (const float*)d_in[7];
    const float* mean   = (const float*)d_in[8];
    const float* var    = (const float*)d_in[9];
    const float* lin1W  = (const float*)d_in[10];
    const float* lin1b  = (const float*)d_in[11];
    const float* lin2W  = (const float*)d_in[12];
    const float* lin2b  = (const float*)d_in[13];
    float* out = (float*)d_out;

    const int* src = ei;
    const int* dst = ei + N_EDGES;

    const int WTOT = 128 * 256 + 3 * 256 * 256; // 229376

    float* ws = (float*)d_ws;
    float* xbuf = ws;                                    // N*HID fp32 (layer3 out, chunk-major)
    float* hbuf = xbuf + (size_t)N_NODES * HID;          // N*HID fp32 (H, chunk-major)
    ushort_t* Ahb = (ushort_t*)(hbuf + (size_t)N_NODES * HID); // N*HID
    ushort_t* Alb = Ahb + (size_t)N_NODES * HID;         // N*HID
    ushort_t* WhT = Alb + (size_t)N_NODES * HID;         // WTOT
    ushort_t* WlT = WhT + WTOT;                          // WTOT
    float* dinv    = (float*)(WlT + WTOT);               // N
    float* selfn   = dinv + N_NODES;                     // N
    float* pooled  = selfn + N_NODES;                    // G*HID
    float* bnscale = pooled + (size_t)N_GRAPHS * HID;    // 4*HID
    float* bnshift = bnscale + N_LAYERS * HID;           // 4*HID
    int*   cnt     = (int*)(bnshift + N_LAYERS * HID);   // G
    int*   degi    = cnt + N_GRAPHS;                     // N
    int*   rowstart= degi + N_NODES;                     // N+1
    int*   cursor  = rowstart + (N_NODES + 1);           // N
    int2*  edata   = (int2*)(cursor + N_NODES);          // E int2

    hipMemsetAsync(degi, 0, (size_t)N_NODES * 4, stream);
    hipMemsetAsync(pooled, 0, (size_t)N_GRAPHS * HID * 4, stream);
    hipMemsetAsync(cnt, 0, (size_t)N_GRAPHS * 4, stream);

    // CSR build + norms
    k_deg<<<(N_EDGES + 255) / 256, 256, 0, stream>>>(dst, degi, N_EDGES);
    k_nodenorm<<<(N_NODES + 255) / 256, 256, 0, stream>>>(degi, dinv, selfn, N_NODES);
    k_scan<<<1, 1024, 0, stream>>>(degi, rowstart, cursor, N_NODES);
    k_fill<<<(N_EDGES + 255) / 256, 256, 0, stream>>>(src, dst, dinv, cursor, edata, N_EDGES);

    // prep
    k_bnprep<<<N_LAYERS, 256, 0, stream>>>(gamma, beta, mean, var, convB, bnscale, bnshift);
    k_splitw<<<(WTOT + 255) / 256, 256, 0, stream>>>(convW0, convWs, WhT, WlT);
    k_splitx<<<(N_NODES * IN_DIM / 4 + 255) / 256, 256, 0, stream>>>(x, Ahb, Alb, N_NODES * IN_DIM / 4);

    dim3 gg((N_NODES + 127) / 128, HID / 128);
    for (int l = 0; l < N_LAYERS; ++l) {
        int K = (l == 0) ? IN_DIM : HID;
        size_t woff = (l == 0) ? 0 : (size_t)(32768 + (l - 1) * 65536);
        k_gemm<<<gg, 256, 0, stream>>>(Ahb, Alb, WhT + woff, WlT + woff, hbuf, K);
        if (l < N_LAYERS - 1)
            k_gather_bf<<<16 * GNB, 256, 0, stream>>>(hbuf, rowstart, edata, selfn,
                                                      bnscale + l * HID, bnshift + l * HID,
                                                      Ahb, Alb);
        else
            k_gather_f32<<<16 * GNB, 256, 0, stream>>>(hbuf, rowstart, edata, selfn,
                                                       bnscale + l * HID, bnshift + l * HID,
                                                       xbuf);
    }

    k_pool<<<(N_NODES + POOL_SPAN - 1) / POOL_SPAN, 256, 0, stream>>>(xbuf, batch, pooled, cnt, N_NODES);
    k_mlp<<<N_GRAPHS, 128, 0, stream>>>(pooled, cnt, lin1W, lin1b, lin2W, lin2b, out);
}